// Round 6
// baseline (369.608 us; speedup 1.0000x reference)
//
#include <hip/hip_runtime.h>
#include <hip/hip_bf16.h>
#include <cstdint>
#include <cstddef>

// JacobiKANLinear: DEGREE=5, A=B=1.0. Inputs fp32, output fp32 (HW-verified r1/r2/r5).
// v7: overlap-structured fused GEMM. r5 analysis: step=5680cyc = VALU 2613 +
// MFMA 1546 + slop 1500; As single-buffering forced VALU/MFMA phase alternation.
// Now: As double-buffered, expansion computed in-region (registers), B staged
// global->reg->LDS (T14) so Bs stays single (LDS 72KB, 2 blocks/CU), and the
// inter-barrier serial region is just 12 ds_writes.
#define BATCH   8192
#define IN_F    1024
#define OUT_F   1024
#define KAUG    (6 * 1024)   // k = i*6 + j ; j=0 -> base weight (silu), j=1..5 -> P_j
#define NSTEP   64           // K-steps: 6144 / 96

typedef __bf16 bf16x8 __attribute__((ext_vector_type(8)));
typedef float  f32x4  __attribute__((ext_vector_type(4)));

// Workspace layout (bytes), ~12.6 MB:
static constexpr size_t WAUG_B    = (size_t)OUT_F * KAUG * 2;        // 12,582,912
static constexpr size_t BIAS2_OFF = WAUG_B;                          // 4 KB f32

// Jacobi recurrence for A=B=1 (beta_n = 0): P_k = (a_k t)P_{k-1} - (b_k)P_{k-2}
constexpr float JA[4] = {64.f/120.f, 180.f/336.f, 384.f/720.f, 700.f/1320.f};
constexpr float JB[4] = {48.f/120.f, 144.f/336.f, 320.f/720.f, 600.f/1320.f};

__device__ __forceinline__ unsigned short f2bf(float f)
{
    __hip_bfloat16 h = __float2bfloat16(f);
    return *(unsigned short*)&h;
}
__device__ __forceinline__ unsigned pack2(float lo, float hi)   // RNE (prep path)
{
    return (unsigned)f2bf(lo) | ((unsigned)f2bf(hi) << 16);
}
// Fast packed conversion: D[15:0]=bf16(lo), D[31:16]=bf16(hi).
__device__ __forceinline__ unsigned cvt_pk(float lo, float hi)
{
    unsigned r;
    asm("v_cvt_pk_bf16_f32 %0, %1, %2" : "=v"(r) : "v"(lo), "v"(hi));
    return r;
}

// ---------------- prep: weights + bias fold only (1024 blocks, v6 verbatim) ---
__global__ void prep_w(const float* __restrict__ W,
                       const float* __restrict__ C,
                       const float* __restrict__ bias,
                       __hip_bfloat16* __restrict__ Waug,
                       float* __restrict__ bias2)
{
    const int o = blockIdx.x;
    const int tid = threadIdx.x;

    __shared__ __align__(16) float cs[IN_F * 6];   // 24 KB
    __shared__ float red[4];

    const float4* C4  = (const float4*)(C + (size_t)o * IN_F * 6);
    float4*       cs4 = (float4*)cs;
#pragma unroll
    for (int k = 0; k < 6; ++k) cs4[tid + k * 256] = C4[tid + k * 256];

    const float4 wv = ((const float4*)(W + (size_t)o * IN_F))[tid];
    const float w4[4] = {wv.x, wv.y, wv.z, wv.w};

    __syncthreads();

    float f[24];
#pragma unroll
    for (int q = 0; q < 6; ++q) {
        const float4 v = cs4[tid * 6 + q];
        f[q * 4 + 0] = v.x; f[q * 4 + 1] = v.y; f[q * 4 + 2] = v.z; f[q * 4 + 3] = v.w;
    }

    unsigned pk[12];
#pragma unroll
    for (int q = 0; q < 4; ++q) {
        pk[q * 3 + 0] = pack2(w4[q],        f[q * 6 + 1]);
        pk[q * 3 + 1] = pack2(f[q * 6 + 2], f[q * 6 + 3]);
        pk[q * 3 + 2] = pack2(f[q * 6 + 4], f[q * 6 + 5]);
    }

    float s = f[0] + f[6] + f[12] + f[18];        // j=0 terms
#pragma unroll
    for (int off = 32; off > 0; off >>= 1) s += __shfl_down(s, off, 64);
    if ((tid & 63) == 0) red[tid >> 6] = s;

    __syncthreads();
    uint4* csU = (uint4*)cs;
    csU[tid * 3 + 0] = make_uint4(pk[0], pk[1], pk[2],  pk[3]);
    csU[tid * 3 + 1] = make_uint4(pk[4], pk[5], pk[6],  pk[7]);
    csU[tid * 3 + 2] = make_uint4(pk[8], pk[9], pk[10], pk[11]);
    __syncthreads();

    uint4* out4 = (uint4*)(Waug + (size_t)o * KAUG);
#pragma unroll
    for (int k = 0; k < 3; ++k) out4[tid + k * 256] = csU[tid + k * 256];

    if (tid == 0) bias2[o] = bias[o] + red[0] + red[1] + red[2] + red[3];
}

// ---------------- fused GEMM v7 ----------------
// 128x128 tile, BK=96 (16 inputs), 256 threads (2x2 waves, 64x64/wave).
// LDS 72 KB = As0(24) | As1(24) | Bs(24)  -> 2 blocks/CU.
// Step t: [big region: MFMA(t) on As[t&1]+Bs ; expand(t+1)->pk regs ;
//          issue B(t+1)->breg, x(t+2)->xn regs] -> sync -> [12 ds_writes:
//          As[(t+1)&1]<-pk, Bs<-breg] -> sync.
// __syncthreads' implicit vmcnt(0) only sees region-top loads aged by the whole
// MFMA+expansion phase (r0-proven aging). Compiler inserts reg-dep waits for
// breg/xn uses. Buffer discipline: MFMA(t) reads As[t&1] (written small-region
// t-1) and Bs=B(t) (written small-region t-1); writes target As[(t+1)&1] (last
// read at t-1) and Bs after all t reads -> no WAR races across the barriers.

#define AS_B    24576                 // per As buffer (128 rows x 192 B)
#define SMEM_B  (3 * 24576)           // 73728

// Expand 8 inputs -> 12 packed bf16 pairs (silu, P1..P5) in registers.
__device__ __forceinline__ void expand8r(const float4 x0, const float4 x1, unsigned* pk)
{
    const float xs[8] = {x0.x, x0.y, x0.z, x0.w, x1.x, x1.y, x1.z, x1.w};
#pragma unroll
    for (int e = 0; e < 8; ++e) {
        const float x  = xs[e];
        // v = e^-x, clamped so u = v*v stays finite (x <= -43: sig->0, t->-1)
        const float v  = __expf(fminf(-x, 43.f));
        const float sg = __builtin_amdgcn_rcpf(1.f + v);
        const float s  = x * sg;                                       // silu
        const float u  = v * v;                                        // e^-2x
        const float tt = (1.f - u) * __builtin_amdgcn_rcpf(1.f + u);   // tanh
        const float p1 = 2.f * tt;
        const float p2 = JA[0] * tt * p1 - JB[0];
        const float p3 = JA[1] * tt * p2 - JB[1] * p1;
        const float p4 = JA[2] * tt * p3 - JB[2] * p2;
        const float p5 = JA[3] * tt * p4 - JB[3] * p3;
        pk[e * 3 + 0] = cvt_pk(s,  p1);
        pk[e * 3 + 1] = cvt_pk(p2, p3);
        pk[e * 3 + 2] = cvt_pk(p4, p5);
    }
}

__global__ __launch_bounds__(256, 2)
void gemm_kan(const float* __restrict__ X,
              const __hip_bfloat16* __restrict__ Waug,
              const float* __restrict__ bias2,
              float* __restrict__ out)
{
    extern __shared__ __align__(16) char smem[];   // [As0 | As1 | Bs]

    const int tid  = threadIdx.x;
    const int lane = tid & 63;
    const int wave = tid >> 6;
    const int wm = wave & 1, wn = wave >> 1;
    const int mBase = blockIdx.x * 128;            // M fastest -> XCD = bx % 8
    const int nBase = blockIdx.y * 128;

    // ---- x source: row tid>>1, inputs (tid&1)*8 .. +7 ----
    const float* gx = X + (size_t)(mBase + (tid >> 1)) * IN_F + (tid & 1) * 8;
    char* const awp = smem + (tid >> 1) * 192 + (tid & 1) * 96;  // within an As buf

    // ---- B chunk map: 6 x 16B per thread; ds_write target linear in chunk idx --
    const __hip_bfloat16* gB[6];
#pragma unroll
    for (int q = 0; q < 6; ++q) {
        const int ci = (q * 4 + wave) * 64 + lane;   // chunk idx in 24 KB tile
        const int br = ci / 12, bc = ci - br * 12;   // row 0..127, chunk 0..11
        gB[q] = Waug + (size_t)(nBase + br) * KAUG + bc * 8;
    }
    char* const bsW = smem + 2 * AS_B + wave * 1024 + lane * 16;  // + q*4096 imm

    // ---- fragment offsets (16B-vector units) ----
    const int quad = lane >> 4, mr = lane & 15;
    const int aoff = (wm * 64 + mr) * 12 + quad;
    const int boff = 2 * (AS_B / 16) + (wn * 64 + mr) * 12 + quad;

    f32x4 acc[4][4] = {};
    unsigned pk[24];
    uint4 breg[6];

    // ---- prologue: x(0)->xc, B(0)->breg, x(1)->xn; As0<-expand(0); Bs<-B(0) ----
    float4 xc0 = *(const float4*)(gx);
    float4 xc1 = *(const float4*)(gx + 4);
#pragma unroll
    for (int q = 0; q < 6; ++q) breg[q] = *(const uint4*)(gB[q]);
    float4 xn0 = *(const float4*)(gx + 16);
    float4 xn1 = *(const float4*)(gx + 20);

    expand8r(xc0, xc1, pk);
#pragma unroll
    for (int j = 0; j < 6; ++j)
        *(uint4*)(awp + j * 16) = make_uint4(pk[j * 4], pk[j * 4 + 1],
                                             pk[j * 4 + 2], pk[j * 4 + 3]);
#pragma unroll
    for (int q = 0; q < 6; ++q) *(uint4*)(bsW + q * 4096) = breg[q];
    __syncthreads();

    const bf16x8* V = (const bf16x8*)smem;

#pragma unroll 1
    for (int t = 0; t < NSTEP; ++t) {
        // ===== big region: issues -> MFMA(t) -> expand(t+1) =====
        xc0 = xn0; xc1 = xn1;                        // x(t+1) (aged one region)
        if (t + 2 < NSTEP) {
            xn0 = *(const float4*)(gx + (size_t)(t + 2) * 16);
            xn1 = *(const float4*)(gx + (size_t)(t + 2) * 16 + 4);
        }
        if (t + 1 < NSTEP) {
#pragma unroll
            for (int q = 0; q < 6; ++q)
                breg[q] = *(const uint4*)(gB[q] + (size_t)(t + 1) * 96);
        }

        const int abase = (t & 1) * (AS_B / 16) + aoff;
#pragma unroll
        for (int kc = 0; kc < 3; ++kc) {
            bf16x8 a[4], b[4];
#pragma unroll
            for (int t4 = 0; t4 < 4; ++t4) a[t4] = V[abase + t4 * 192 + kc * 4];
#pragma unroll
            for (int t4 = 0; t4 < 4; ++t4) b[t4] = V[boff + t4 * 192 + kc * 4];
#pragma unroll
            for (int i = 0; i < 4; ++i)
#pragma unroll
                for (int jj = 0; jj < 4; ++jj)
                    acc[i][jj] = __builtin_amdgcn_mfma_f32_16x16x32_bf16(
                        a[i], b[jj], acc[i][jj], 0, 0, 0);
        }

        if (t + 1 < NSTEP) expand8r(xc0, xc1, pk);   // VALU fills under MFMA drain

        __syncthreads();   // all MFMA(t) LDS reads done; region-top vmem aged

        // ===== small region: 12 ds_writes only =====
        if (t + 1 < NSTEP) {
            char* const asd = awp + ((t + 1) & 1) * AS_B;
#pragma unroll
            for (int j = 0; j < 6; ++j)
                *(uint4*)(asd + j * 16) = make_uint4(pk[j * 4], pk[j * 4 + 1],
                                                     pk[j * 4 + 2], pk[j * 4 + 3]);
#pragma unroll
            for (int q = 0; q < 6; ++q) *(uint4*)(bsW + q * 4096) = breg[q];
        }
        __syncthreads();   // writes visible for step t+1
    }

    // ---- direct-store epilogue; C/D map hardcoded (m89-verified: row_in_16 =
    // quad*4+r, col = mr — matched the probe every measured run) ----
#pragma unroll
    for (int i = 0; i < 4; ++i) {
#pragma unroll
        for (int jj = 0; jj < 4; ++jj) {
            const int col = nBase + wn * 64 + jj * 16 + mr;
            const float b2 = bias2[col];
#pragma unroll
            for (int r = 0; r < 4; ++r) {
                const int row = mBase + wm * 64 + i * 16 + quad * 4 + r;
                out[(size_t)row * OUT_F + col] = acc[i][jj][r] + b2;
            }
        }
    }
}

// ---------------- launch ----------------

extern "C" void kernel_launch(void* const* d_in, const int* in_sizes, int n_in,
                              void* d_out, int out_size, void* d_ws, size_t ws_size,
                              hipStream_t stream)
{
    (void)out_size; (void)ws_size;
    const float* x    = (const float*)d_in[0];
    const float* W    = (const float*)d_in[1];
    const float* C    = (const float*)d_in[2];
    const float* bias = (const float*)d_in[3];
    for (int i = 0; i < n_in; ++i) {
        if      (in_sizes[i] == BATCH * IN_F)     x    = (const float*)d_in[i];
        else if (in_sizes[i] == OUT_F * IN_F)     W    = (const float*)d_in[i];
        else if (in_sizes[i] == OUT_F * IN_F * 6) C    = (const float*)d_in[i];
        else if (in_sizes[i] == OUT_F)            bias = (const float*)d_in[i];
    }
    float* out = (float*)d_out;
    char* ws = (char*)d_ws;
    __hip_bfloat16* Waug  = (__hip_bfloat16*)ws;
    float*          bias2 = (float*)(ws + BIAS2_OFF);

    // 72 KB dynamic LDS (> 64 KB default): opt in once (proven path, r1).
    static bool smem_attr_done = false;
    if (!smem_attr_done) {
        (void)hipFuncSetAttribute((const void*)gemm_kan,
                                  hipFuncAttributeMaxDynamicSharedMemorySize,
                                  SMEM_B);
        smem_attr_done = true;
    }

    prep_w<<<dim3(OUT_F), dim3(256), 0, stream>>>(W, C, bias, Waug, bias2);
    gemm_kan<<<dim3(BATCH / 128, OUT_F / 128), dim3(256), SMEM_B, stream>>>(
        x, Waug, bias2, out);
}

// Round 7
// 223.724 us; speedup vs baseline: 1.6521x; 1.6521x over previous
//
#include <hip/hip_runtime.h>
#include <hip/hip_bf16.h>
#include <cstdint>
#include <cstddef>

// JacobiKANLinear: DEGREE=5, A=B=1.0. Inputs fp32, output fp32 (HW-verified r1/r2/r5).
// v8 = v6 (best measured: gemm 151us) + MONOMIAL BASIS:
//   Sum_j c_j P_j(t) == Sum_m c'_m t^m with c' = M c folded into Waug (prep_w).
//   A-slab becomes [silu, t, t^2..t^5]: expansion loses the 9-FMA Jacobi
//   recurrence (-38% VALU/elem). Even-degree constant terms fold into bias2.
// r6 lesson: v7's reg-staged schedule spilled to scratch (WRITE_SIZE 33->262MB,
// VGPR 80) -> reverted; keep v6's proven structure everywhere else.
#define BATCH   8192
#define IN_F    1024
#define OUT_F   1024
#define KAUG    (6 * 1024)   // k = i*6 + m ; m=0 -> base weight (silu), m=1..5 -> t^m
#define NSTEP   64           // K-steps: 6144 / 96

typedef __bf16 bf16x8 __attribute__((ext_vector_type(8)));
typedef float  f32x4  __attribute__((ext_vector_type(4)));

// Workspace layout (bytes), ~12.6 MB:
static constexpr size_t WAUG_B    = (size_t)OUT_F * KAUG * 2;        // 12,582,912
static constexpr size_t BIAS2_OFF = WAUG_B;                          // 4 KB f32

// Monomial coefficients of the reference's P_j recurrence (A=B=1, exact):
//   P1 = 2t
//   P2 = (16/15)t^2 - 2/5
//   P3 = (4/7)t^3 - (15/14)t
//   P4 = (32/105)t^4 - (988/945)t^2 + 8/45
//   P5 = (16/99)t^5 - 0.8141735129..t^3 + 0.5812890813..t
constexpr float M1_1 = 2.0f;
constexpr float M3_1 = -1.0714285714f;   // -15/14
constexpr float M5_1 =  0.5812890813f;   // 28/297 + 75/154
constexpr float M2_2 =  1.0666666667f;   // 16/15
constexpr float M4_2 = -1.0455026455f;   // -988/945
constexpr float M3_3 =  0.5714285714f;   // 4/7
constexpr float M5_3 = -0.8141735129f;   // -(34580/62370 + 20/77)
constexpr float M4_4 =  0.3047619048f;   // 32/105
constexpr float M5_5 =  0.1616161616f;   // 16/99
constexpr float M2_0 = -0.4f;            // -2/5
constexpr float M4_0 =  0.1777777778f;   // 8/45

__device__ __forceinline__ unsigned short f2bf(float f)
{
    __hip_bfloat16 h = __float2bfloat16(f);
    return *(unsigned short*)&h;
}
__device__ __forceinline__ unsigned pack2(float lo, float hi)   // RNE (prep path)
{
    return (unsigned)f2bf(lo) | ((unsigned)f2bf(hi) << 16);
}
// Fast packed conversion: D[15:0]=bf16(lo), D[31:16]=bf16(hi).
__device__ __forceinline__ unsigned cvt_pk(float lo, float hi)
{
    unsigned r;
    asm("v_cvt_pk_bf16_f32 %0, %1, %2" : "=v"(r) : "v"(lo), "v"(hi));
    return r;
}

// ---------------- prep: weights + bias fold + basis change (1024 blocks) ------
// Waug[o][i*6+0] = bf16(W[o][i]); Waug[o][i*6+m] = bf16(c'_m), m=1..5 where
// c'_m = Sum_j C[o][i][j] * M[j][m]. bias2[o] = bias[o] + Sum_i c'_0(o,i).
__global__ void prep_w(const float* __restrict__ W,
                       const float* __restrict__ C,
                       const float* __restrict__ bias,
                       __hip_bfloat16* __restrict__ Waug,
                       float* __restrict__ bias2)
{
    const int o = blockIdx.x;
    const int tid = threadIdx.x;

    __shared__ __align__(16) float cs[IN_F * 6];   // 24 KB
    __shared__ float red[4];

    // ---- coalesced C-row load: 6 x float4 per thread, lane-consecutive ----
    const float4* C4  = (const float4*)(C + (size_t)o * IN_F * 6);
    float4*       cs4 = (float4*)cs;
#pragma unroll
    for (int k = 0; k < 6; ++k) cs4[tid + k * 256] = C4[tid + k * 256];

    const float4 wv = ((const float4*)(W + (size_t)o * IN_F))[tid];
    const float w4[4] = {wv.x, wv.y, wv.z, wv.w};

    __syncthreads();

    // ---- per-thread gather from LDS: 24 floats = C[o][i..i+3][0..5] ----
    float f[24];
#pragma unroll
    for (int q = 0; q < 6; ++q) {
        const float4 v = cs4[tid * 6 + q];
        f[q * 4 + 0] = v.x; f[q * 4 + 1] = v.y; f[q * 4 + 2] = v.z; f[q * 4 + 3] = v.w;
    }

    unsigned pk[12];
    float s = 0.f;
#pragma unroll
    for (int q = 0; q < 4; ++q) {
        const float c0 = f[q * 6 + 0], c1 = f[q * 6 + 1], c2 = f[q * 6 + 2];
        const float c3 = f[q * 6 + 3], c4 = f[q * 6 + 4], c5 = f[q * 6 + 5];
        const float cp1 = M1_1 * c1 + M3_1 * c3 + M5_1 * c5;
        const float cp2 = M2_2 * c2 + M4_2 * c4;
        const float cp3 = M3_3 * c3 + M5_3 * c5;
        const float cp4 = M4_4 * c4;
        const float cp5 = M5_5 * c5;
        s += c0 + M2_0 * c2 + M4_0 * c4;            // constant terms -> bias
        pk[q * 3 + 0] = pack2(w4[q], cp1);
        pk[q * 3 + 1] = pack2(cp2,   cp3);
        pk[q * 3 + 2] = pack2(cp4,   cp5);
    }

#pragma unroll
    for (int off = 32; off > 0; off >>= 1) s += __shfl_down(s, off, 64);
    if ((tid & 63) == 0) red[tid >> 6] = s;

    __syncthreads();                               // everyone done reading cs
    // ---- restage packed row in LDS (768 uint4 = 12 KB, reuse cs) ----
    uint4* csU = (uint4*)cs;
    csU[tid * 3 + 0] = make_uint4(pk[0], pk[1], pk[2],  pk[3]);
    csU[tid * 3 + 1] = make_uint4(pk[4], pk[5], pk[6],  pk[7]);
    csU[tid * 3 + 2] = make_uint4(pk[8], pk[9], pk[10], pk[11]);
    __syncthreads();

    // ---- coalesced store: 3 x uint4 per thread, lane-consecutive ----
    uint4* out4 = (uint4*)(Waug + (size_t)o * KAUG);
#pragma unroll
    for (int k = 0; k < 3; ++k) out4[tid + k * 256] = csU[tid + k * 256];

    if (tid == 0) bias2[o] = bias[o] + red[0] + red[1] + red[2] + red[3];
}

// ---------------- fused GEMM (v6 structure verbatim; monomial expansion) ------
// 128x128 tile, BK=96 (16 inputs), 256 threads (2x2 waves, 64x64/wave).
// A: computed on the fly from x (fp32) -> regs -> ds_write bf16 (single buffer).
// B: Waug via global_load_lds, double-buffered, issued at top of compute so the
//    __syncthreads vmcnt drain sees loads aged by a full compute phase (r0-proven).
// LDS: As 24 KB + Bs 2x24 KB = 72 KB -> 2 blocks/CU (cross-block overlap, m114).
__device__ __forceinline__ void async_load16(const void* g, void* l)
{
    __builtin_amdgcn_global_load_lds(
        (const __attribute__((address_space(1))) void*)g,
        (__attribute__((address_space(3))) void*)l,
        16, 0, 0);
}

#define AS_B    24576                 // As bytes (128 rows x 192 B)
#define BS_B    24576                 // per-buffer Bs bytes
#define SMEM_B  (AS_B + 2 * BS_B)     // 73728

__global__ __launch_bounds__(256, 2)
void gemm_kan(const float* __restrict__ X,
              const __hip_bfloat16* __restrict__ Waug,
              const float* __restrict__ bias2,
              float* __restrict__ out)
{
    extern __shared__ __align__(16) char smem[];   // [As 24576 | Bs0 24576 | Bs1 24576]

    const int tid  = threadIdx.x;
    const int lane = tid & 63;
    const int wave = tid >> 6;
    const int wm = wave & 1, wn = wave >> 1;
    const int mBase = blockIdx.x * 128;            // M fastest -> XCD = bx % 8
    const int nBase = blockIdx.y * 128;

    // ---- x source for expansion: row tid>>1, inputs (tid&1)*8 .. +7 ----
    const float* gx = X + (size_t)(mBase + (tid >> 1)) * IN_F + (tid & 1) * 8;
    char* const aw = smem + (tid >> 1) * 192 + (tid & 1) * 96;   // thread's 96 B in As

    // ---- B staging: 6 x 16B chunks per thread; LDS dest wave-uniform base ----
    const __hip_bfloat16* gB[6]; int lB[6];
#pragma unroll
    for (int q = 0; q < 6; ++q) {
        const int ci = (q * 4 + wave) * 64 + lane;   // 16B-chunk index in 24 KB tile
        const int br = ci / 12, bc = ci - br * 12;   // row 0..127, chunk 0..11
        gB[q] = Waug + (size_t)(nBase + br) * KAUG + bc * 8;
        lB[q] = AS_B + (q * 4 + wave) * 1024;        // + lane*16 added by HW
    }

    // ---- fragment offsets (16B-vector units) ----
    const int quad = lane >> 4, mr = lane & 15;
    const int aoff = (wm * 64 + mr) * 12 + quad;
    const int boff = (AS_B / 16) + (wn * 64 + mr) * 12 + quad;

    f32x4 acc[4][4] = {};

    // ---- prologue: x(0) to regs; B-stage(0) -> buf0 ----
    float4 xc0 = *(const float4*)(gx);
    float4 xc1 = *(const float4*)(gx + 4);
#pragma unroll
    for (int q = 0; q < 6; ++q) async_load16(gB[q], smem + lB[q]);

#pragma unroll 1
    for (int t = 0; t < NSTEP; ++t) {
        // ---- expand 8 inputs -> [silu, t, t^2..t^5] bf16 (~16 ops/elem) ----
        const float xs[8] = {xc0.x, xc0.y, xc0.z, xc0.w, xc1.x, xc1.y, xc1.z, xc1.w};
        unsigned pk[24];
#pragma unroll
        for (int e = 0; e < 8; ++e) {
            const float x  = xs[e];
            // v = e^-x, clamped so u = v*v stays finite (x <= -43: sig->0, t->-1)
            const float v  = __expf(fminf(-x, 43.f));
            const float sg = __builtin_amdgcn_rcpf(1.f + v);
            const float s  = x * sg;                  // silu(x) = x * sigmoid(x)
            const float u  = v * v;                   // e^-2x
            const float tt = (1.f - u) * __builtin_amdgcn_rcpf(1.f + u);   // tanh(x)
            const float t2 = tt * tt;
            const float t3 = t2 * tt;
            const float t4 = t2 * t2;
            const float t5 = t4 * tt;
            pk[e * 3 + 0] = cvt_pk(s,  tt);
            pk[e * 3 + 1] = cvt_pk(t2, t3);
            pk[e * 3 + 2] = cvt_pk(t4, t5);
        }
        __syncthreads();               // all waves done reading As(t-1); drains aged vmem
        // ---- write As(t) ----
#pragma unroll
        for (int j = 0; j < 6; ++j)
            *(uint4*)(aw + j * 16) = make_uint4(pk[j * 4], pk[j * 4 + 1],
                                                pk[j * 4 + 2], pk[j * 4 + 3]);
        __syncthreads();               // As(t) visible (lgkm drain; no young vmem)

        // ---- issue next-step loads FIRST: they age through the compute phase ----
        if (t + 1 < NSTEP) {
            char* const bs = smem + ((t + 1) & 1) * BS_B;
#pragma unroll
            for (int q = 0; q < 6; ++q) async_load16(gB[q] + (t + 1) * 96, bs + lB[q]);
            xc0 = *(const float4*)(gx + (t + 1) * 16);
            xc1 = *(const float4*)(gx + (t + 1) * 16 + 4);
        }

        // ---- compute: 3 k-chunks x 16 MFMA from As + Bs[t&1] ----
        const bf16x8* V = (const bf16x8*)smem;
        const int bo = boff + (t & 1) * (BS_B / 16);
#pragma unroll
        for (int kc = 0; kc < 3; ++kc) {
            bf16x8 a[4], b[4];
#pragma unroll
            for (int t4 = 0; t4 < 4; ++t4) a[t4] = V[aoff + t4 * 192 + kc * 4];
#pragma unroll
            for (int t4 = 0; t4 < 4; ++t4) b[t4] = V[bo + t4 * 192 + kc * 4];
#pragma unroll
            for (int i = 0; i < 4; ++i)
#pragma unroll
                for (int jj = 0; jj < 4; ++jj)
                    acc[i][jj] = __builtin_amdgcn_mfma_f32_16x16x32_bf16(a[i], b[jj], acc[i][jj], 0, 0, 0);
        }
    }

    // ---- direct-store epilogue; C/D map hardcoded (m89-verified: row_in_16 =
    // quad*4+r, col = mr — matched the probe every measured run) ----
#pragma unroll
    for (int i = 0; i < 4; ++i) {
#pragma unroll
        for (int jj = 0; jj < 4; ++jj) {
            const int col = nBase + wn * 64 + jj * 16 + mr;
            const float b2 = bias2[col];
#pragma unroll
            for (int r = 0; r < 4; ++r) {
                const int row = mBase + wm * 64 + i * 16 + quad * 4 + r;
                out[(size_t)row * OUT_F + col] = acc[i][jj][r] + b2;
            }
        }
    }
}

// ---------------- launch ----------------

extern "C" void kernel_launch(void* const* d_in, const int* in_sizes, int n_in,
                              void* d_out, int out_size, void* d_ws, size_t ws_size,
                              hipStream_t stream)
{
    (void)out_size; (void)ws_size;
    const float* x    = (const float*)d_in[0];
    const float* W    = (const float*)d_in[1];
    const float* C    = (const float*)d_in[2];
    const float* bias = (const float*)d_in[3];
    for (int i = 0; i < n_in; ++i) {
        if      (in_sizes[i] == BATCH * IN_F)     x    = (const float*)d_in[i];
        else if (in_sizes[i] == OUT_F * IN_F)     W    = (const float*)d_in[i];
        else if (in_sizes[i] == OUT_F * IN_F * 6) C    = (const float*)d_in[i];
        else if (in_sizes[i] == OUT_F)            bias = (const float*)d_in[i];
    }
    float* out = (float*)d_out;
    char* ws = (char*)d_ws;
    __hip_bfloat16* Waug  = (__hip_bfloat16*)ws;
    float*          bias2 = (float*)(ws + BIAS2_OFF);

    // 72 KB dynamic LDS (> 64 KB default): opt in once (proven path, r1).
    static bool smem_attr_done = false;
    if (!smem_attr_done) {
        (void)hipFuncSetAttribute((const void*)gemm_kan,
                                  hipFuncAttributeMaxDynamicSharedMemorySize,
                                  SMEM_B);
        smem_attr_done = true;
    }

    prep_w<<<dim3(OUT_F), dim3(256), 0, stream>>>(W, C, bias, Waug, bias2);
    gemm_kan<<<dim3(BATCH / 128, OUT_F / 128), dim3(256), SMEM_B, stream>>>(
        x, Waug, bias2, out);
}